// Round 6
// baseline (125.861 us; speedup 1.0000x reference)
//
#include <hip/hip_runtime.h>
#include <hip/hip_bf16.h>

typedef __attribute__((ext_vector_type(8))) short short8;
typedef __attribute__((ext_vector_type(4))) float float4v;

#define N_ROWS 4096
#define K_DIM  192
#define NTILE  1056                      // 272 XX + 272 YY + 512 XY (256x128 tiles)
#define GRID_P 256                       // persistent blocks (1 per CU)
#define STRB   208                       // LDS row stride bytes (104 bf16: 96 + 8 pad)
#define STG    79872                     // 384 rows * 208 B per stage region
#define LDS_TOTAL (2 * STG + 64)
#define C1     (-0.72134752044448179f)   // -0.5*log2(e)
#define LOG2E  (1.4426950408889634f)

// ---- kernel 1: fp32 -> bf16 convert + per-row sum of squares (of bf16 values) ----
__global__ void prep_kernel(const float* __restrict__ x, const float* __restrict__ y,
                            __hip_bfloat16* __restrict__ xb, __hip_bfloat16* __restrict__ yb,
                            float* __restrict__ sqx, float* __restrict__ sqy)
{
    int w    = (blockIdx.x * blockDim.x + threadIdx.x) >> 6;  // one row per wave
    int lane = threadIdx.x & 63;
    if (w >= 2 * N_ROWS) return;
    const float*      src = (w < N_ROWS) ? (x + (size_t)w * K_DIM) : (y + (size_t)(w - N_ROWS) * K_DIM);
    __hip_bfloat16*   dst = (w < N_ROWS) ? (xb + (size_t)w * K_DIM) : (yb + (size_t)(w - N_ROWS) * K_DIM);
    float s = 0.f;
    #pragma unroll
    for (int i = 0; i < 3; ++i) {
        float f = src[lane + 64 * i];
        __hip_bfloat16 h = __float2bfloat16(f);
        dst[lane + 64 * i] = h;
        float fb = __bfloat162float(h);
        s += fb * fb;
    }
    #pragma unroll
    for (int off = 32; off; off >>= 1) s += __shfl_down(s, off, 64);
    if (lane == 0) {
        if (w < N_ROWS) sqx[w] = s; else sqy[w - N_ROWS] = s;
    }
}

// ---- tile metadata: id -> class / panels / weights ----
struct TileMeta {
    const short* A; const short* B; const float* sa; const float* sb;
    int ab, bb; float wgt;               // wgt is per-wave (depends on wm row-half)
};

__device__ __forceinline__ TileMeta tile_meta(int id, const short* xbs, const short* ybs,
                                              const float* sqx, const float* sqy, int wm)
{
    TileMeta m; int cls, t, bi2, bj;
    if (id < 544) {
        if (id < 272) { cls = 0; t = id; } else { cls = 1; t = id - 272; }
        bi2 = 0;
        for (;;) { int nb = 32 - 2 * bi2; if (t < nb) break; t -= nb; ++bi2; }
        bj = 2 * bi2 + t;
    } else { cls = 2; t = id - 544; bi2 = t >> 5; bj = t & 31; }
    if (cls == 0)      { m.A = xbs; m.B = xbs; m.sa = sqx; m.sb = sqx; }
    else if (cls == 1) { m.A = ybs; m.B = ybs; m.sa = sqy; m.sb = sqy; }
    else               { m.A = xbs; m.B = ybs; m.sa = sqx; m.sb = sqy; }
    m.ab = bi2 * 256; m.bb = bj * 128;
    if (cls < 2) {
        int r128 = 2 * bi2 + (wm >> 1);          // which 128-row half this wave is in
        m.wgt = (bj < r128) ? 0.0f : ((bj == r128) ? 1.0f : 2.0f);
    } else m.wgt = -2.0f;                         // XY enters mmd as -2*Sxy
    return m;
}

// ---- kernel 2: persistent fused Gram + exp + reduce ----
// 256 blocks x 512 thr (8 waves, 1 block/CU via 160KB LDS). Each block loops
// over 4-5 tiles of 256x128. K=192 = 2 stages of 96 ping-ponged between two
// LDS regions; VGPR staging; rotation = [ds_write vS; barrier; load vS+1;
// compute S] -> prefetch distance one stage, no VM ops outstanding at barriers.
extern __shared__ char smem[];

__global__ __launch_bounds__(512, 2)
void gram_persist(const __hip_bfloat16* __restrict__ xb_, const __hip_bfloat16* __restrict__ yb_,
                  const float* __restrict__ sqx, const float* __restrict__ sqy,
                  float* __restrict__ partials)
{
    const short* xbs = (const short*)xb_;
    const short* ybs = (const short*)yb_;
    const int tid  = threadIdx.x, lane = tid & 63, w = tid >> 6;
    const int wm   = w & 3, wn = w >> 2;          // wm: 64-row quad, wn: 64-col half
    const int m15  = lane & 15, quad = lane >> 4;

    // per-lane staging map: 9 x 16B chunks per stage (384 rows x 12 chunks)
    int rel[9], isB[9], loff[9];
    #pragma unroll
    for (int i = 0; i < 9; ++i) {
        int c   = tid + 512 * i;                  // 0..4607
        int row = (c * 10923) >> 17;              // c / 12 exact in range
        int cw  = c - row * 12;
        int r2  = (row < 256) ? row : row - 256;
        rel[i]  = r2 * 384 + cw * 16;             // bytes within panel (row = 384B)
        isB[i]  = (row >= 256);
        loff[i] = row * STRB + cw * 16;           // padded LDS offset
    }

    // fragment LDS row bases (A rows 0..255, B rows 256..383)
    int rbA[4], rbB[4];
    #pragma unroll
    for (int q = 0; q < 4; ++q) {
        rbA[q] = (wm * 64 + q * 16 + m15) * STRB + quad * 16;
        rbB[q] = (256 + wn * 64 + q * 16 + m15) * STRB + quad * 16;
    }

    float total = 0.f;
    const int tcount = (blockIdx.x < NTILE - 4 * GRID_P) ? 5 : 4;

    // prologue: tile 0 meta + issue its stage-0 loads
    TileMeta mt = tile_meta(blockIdx.x, xbs, ybs, sqx, sqy, wm);
    const char* Ap = (const char*)(mt.A + (size_t)mt.ab * K_DIM);
    const char* Bp = (const char*)(mt.B + (size_t)mt.bb * K_DIM);
    uint4 v[9];
    #pragma unroll
    for (int i = 0; i < 9; ++i) v[i] = *(const uint4*)((isB[i] ? Bp : Ap) + rel[i]);

    for (int k = 0; k < tcount; ++k) {
        float4v acc[4][4];
        #pragma unroll
        for (int a = 0; a < 4; ++a)
            #pragma unroll
            for (int b = 0; b < 4; ++b) acc[a][b] = (float4v){0.f, 0.f, 0.f, 0.f};

        float wgt = mt.wgt;
        const float* sa = mt.sa; const float* sb = mt.sb;
        const int ab = mt.ab, bb = mt.bb;

        // ---- stage 0: write v (region 0), barrier, prefetch stage 1, compute ----
        #pragma unroll
        for (int i = 0; i < 9; ++i) *(uint4*)(smem + loff[i]) = v[i];
        __syncthreads();
        // sq terms + stage-1 loads (consumed next stage / epilogue — fully covered)
        float4v ua[4]; float vb4[4];
        #pragma unroll
        for (int tm = 0; tm < 4; ++tm)
            ua[tm] = (*(const float4v*)&sa[ab + wm * 64 + tm * 16 + quad * 4]) * C1;
        #pragma unroll
        for (int tn = 0; tn < 4; ++tn)
            vb4[tn] = C1 * sb[bb + wn * 64 + tn * 16 + m15];
        #pragma unroll
        for (int i = 0; i < 9; ++i) v[i] = *(const uint4*)((isB[i] ? Bp : Ap) + rel[i] + 192);

        #pragma unroll
        for (int ks = 0; ks < 3; ++ks) {
            short8 af[4], bf[4];
            #pragma unroll
            for (int tm = 0; tm < 4; ++tm) af[tm] = *(const short8*)(smem + rbA[tm] + ks * 64);
            #pragma unroll
            for (int tn = 0; tn < 4; ++tn) bf[tn] = *(const short8*)(smem + rbB[tn] + ks * 64);
            #pragma unroll
            for (int tm = 0; tm < 4; ++tm)
                #pragma unroll
                for (int tn = 0; tn < 4; ++tn)
                    acc[tm][tn] = __builtin_amdgcn_mfma_f32_16x16x32_bf16(af[tm], bf[tn], acc[tm][tn], 0, 0, 0);
        }

        // ---- stage 1: write v (region 1), next-tile meta, barrier, prefetch, compute ----
        #pragma unroll
        for (int i = 0; i < 9; ++i) *(uint4*)(smem + STG + loff[i]) = v[i];
        bool more = (k + 1 < tcount);
        if (more) {
            mt = tile_meta(blockIdx.x + GRID_P * (k + 1), xbs, ybs, sqx, sqy, wm);
            Ap = (const char*)(mt.A + (size_t)mt.ab * K_DIM);
            Bp = (const char*)(mt.B + (size_t)mt.bb * K_DIM);
        }
        __syncthreads();
        if (more) {
            #pragma unroll
            for (int i = 0; i < 9; ++i) v[i] = *(const uint4*)((isB[i] ? Bp : Ap) + rel[i]);
        }

        #pragma unroll
        for (int ks = 0; ks < 3; ++ks) {
            short8 af[4], bf[4];
            #pragma unroll
            for (int tm = 0; tm < 4; ++tm) af[tm] = *(const short8*)(smem + STG + rbA[tm] + ks * 64);
            #pragma unroll
            for (int tn = 0; tn < 4; ++tn) bf[tn] = *(const short8*)(smem + STG + rbB[tn] + ks * 64);
            #pragma unroll
            for (int tm = 0; tm < 4; ++tm)
                #pragma unroll
                for (int tn = 0; tn < 4; ++tn)
                    acc[tm][tn] = __builtin_amdgcn_mfma_f32_16x16x32_bf16(af[tm], bf[tn], acc[tm][tn], 0, 0, 0);
        }

        // ---- epilogue: weighted exp-sum (ballot skips underflowing 16x16 tiles) ----
        float lsum = 0.f;
        #pragma unroll
        for (int tm = 0; tm < 4; ++tm)
            #pragma unroll
            for (int tn = 0; tn < 4; ++tn) {
                float vv = vb4[tn];
                float s0 = fminf(ua[tm][0] + vv + LOG2E * acc[tm][tn][0], 0.f);
                float s1 = fminf(ua[tm][1] + vv + LOG2E * acc[tm][tn][1], 0.f);
                float s2 = fminf(ua[tm][2] + vv + LOG2E * acc[tm][tn][2], 0.f);
                float s3 = fminf(ua[tm][3] + vv + LOG2E * acc[tm][tn][3], 0.f);
                float mx = fmaxf(fmaxf(s0, s1), fmaxf(s2, s3));
                if (__ballot(mx > -40.f)) {
                    lsum += __builtin_amdgcn_exp2f(s0) + __builtin_amdgcn_exp2f(s1)
                          + __builtin_amdgcn_exp2f(s2) + __builtin_amdgcn_exp2f(s3);
                }
            }
        total += wgt * lsum;
    }

    // ---- block reduce ----
    #pragma unroll
    for (int off = 32; off; off >>= 1) total += __shfl_down(total, off, 64);
    float* wred = (float*)(smem + 2 * STG);
    if (lane == 0) wred[w] = total;
    __syncthreads();
    if (tid == 0) {
        float p = 0.f;
        #pragma unroll
        for (int i = 0; i < 8; ++i) p += wred[i];
        partials[blockIdx.x] = p;
    }
}

// ---- kernel 3: final reduce + loss ----
__global__ void final_kernel(const float* __restrict__ partials, const float* __restrict__ avg_step,
                             float* __restrict__ out)
{
    __shared__ float red[4];
    int tid = threadIdx.x, lane = tid & 63, w = tid >> 6;
    float s = partials[tid];                          // 256 threads, 256 partials
    #pragma unroll
    for (int off = 32; off; off >>= 1) s += __shfl_down(s, off, 64);
    if (lane == 0) red[w] = s;
    __syncthreads();
    if (tid == 0) {
        float sum = red[0] + red[1] + red[2] + red[3];  // = Sxx + Syy - 2*Sxy
        const float inv = 1.0f / 16777216.0f;           // 1/4096^2
        float mmd   = sum * inv;
        float stepv = fmaxf(1.0f, avg_step[0]);
        out[0] = mmd + (stepv - 1.0f) * 0.002f;
        out[1] = mmd;
    }
}

extern "C" void kernel_launch(void* const* d_in, const int* in_sizes, int n_in,
                              void* d_out, int out_size, void* d_ws, size_t ws_size,
                              hipStream_t stream)
{
    const float* x        = (const float*)d_in[0];
    const float* y        = (const float*)d_in[1];
    const float* avg_step = (const float*)d_in[2];

    char* ws = (char*)d_ws;
    __hip_bfloat16* xb       = (__hip_bfloat16*)(ws);
    __hip_bfloat16* yb       = (__hip_bfloat16*)(ws + 1572864);
    float*          sqx      = (float*)(ws + 3145728);
    float*          sqy      = (float*)(ws + 3162112);
    float*          partials = (float*)(ws + 3178496);

    hipFuncSetAttribute(reinterpret_cast<const void*>(gram_persist),
                        hipFuncAttributeMaxDynamicSharedMemorySize, LDS_TOTAL);

    prep_kernel<<<2048, 256, 0, stream>>>(x, y, xb, yb, sqx, sqy);
    gram_persist<<<GRID_P, 512, LDS_TOTAL, stream>>>(xb, yb, sqx, sqy, partials);
    final_kernel<<<1, 256, 0, stream>>>(partials, avg_step, (float*)d_out);
}